// Round 13
// baseline (116.522 us; speedup 1.0000x reference)
//
#include <hip/hip_runtime.h>

// ============================================================================
// 7-layer MLP (3->40x6->3, tanh) via f16 MFMA + dual-pipe tanh, 64 pts/wave.
//
// r12 postmortem: dur pinned 112-121us across 6 structural variants; VALU
// ~73% busy, no pipe saturated, occupancy metric unreliable. Hypothesis: the
// per-pair {ds_read, ds_read, asm mix, asm mix} pattern makes hipcc emit a
// conservative lgkmcnt wait per pair (timid scheduling around inline asm) ->
// serial ds latency exposure. r13: phase-split ACT. Per tile-layer:
//   D1 MFMAs -> issue D1's 4 table loads -> D0 MFMAs (cover loads) ->
//   issue D0's 12 loads -> exp-path words (trans ops run while loads fly) ->
//   all 8 mix-pairs consume. One counted waitcnt instead of 8 serial ones.
// Same arithmetic per value -> absmax must stay 0.0039.
//
// MFMA layout contracts (gfx950 v_mfma_f32_32x32x16_f16), verified r3-r12:
//   A: row = lane&31, k = 8*(lane>>5)+i   B: col = lane&31, same k packing
//   D: col = lane&31, row = (reg&3) + 8*(reg>>2) + 4*(lane>>5)
// K-columns permuted (kappa) so D->B repack is in-lane. Verified identity:
// P := 4*(kap>>4) + ((kap&7)>>1) == Bf word index, all 40 neurons.
// Exp rows (words 0..1) pre-scaled 2/ln2: tanh = 1-2*rcp(1+2^y), exact.
// Table rows pre-scaled 32 + offset col 112 (MFMA emits u = (x+3.5)*32).
// Table: 225 entries, packed f16 {base,delta}/u32, 32-replica in LDS ->
// bank == lane&31 -> conflict-free (verified r7: conflicts 1.6e7 -> 0).
// Weight frags in GLOBAL d_ws (L1/L2-resident, r12). ws = 36.7 KB total
// (r6 ERRATA: 64.6 KB overflowed ws -> poisoned table tail).
// ============================================================================

typedef _Float16 f16x8 __attribute__((ext_vector_type(8)));
typedef float    f32x16 __attribute__((ext_vector_type(16)));
typedef unsigned int u32x4 __attribute__((ext_vector_type(4)));

#define NFRAG  35        // L0: 2, L1..5: 6 each, L6: 3
#define TABN   225       // entries, domain [-3.5, 3.5], h = 1/32
#define TABREP 32        // LDS replication -> bank = lane&31, conflict-free
#define SEXP   2         // Bf words 0..1 (8 rows/layer) via exp path
#define INVH   32.0f
#define UOFF   112.0f    // 3.5*32, exact in f16
#define UMAX   223.999f
#define TABR   3.5f
#define EXPSC  2.8853900817779268f   // 2/ln(2)

// k-slot -> input neuron; -2 = bias, -3 = offset const, -1 = zero pad
__constant__ int INV[48] = {
     0,  1,  2,  3,   8,  9, 10, 11,   4,  5,  6,  7,  12, 13, 14, 15,
    16, 17, 18, 19,  24, 25, 26, 27,  20, 21, 22, 23,  28, 29, 30, 31,
    32, 33, 34, 35,  -1, -1, -1, -1,  36, 37, 38, 39,  -2, -3, -1, -1 };

// output neuron j -> k-slot (kappa); P(j) = 4*(kap>>4) + ((kap&7)>>1) = word
__constant__ int KAP[40] = {
     0,  1,  2,  3,   8,  9, 10, 11,   4,  5,  6,  7,  12, 13, 14, 15,
    16, 17, 18, 19,  24, 25, 26, 27,  20, 21, 22, 23,  28, 29, 30, 31,
    32, 33, 34, 35,  40, 41, 42, 43 };

__global__ void prep_frags(const float* __restrict__ W0, const float* __restrict__ b0,
                           const float* __restrict__ W1, const float* __restrict__ b1,
                           const float* __restrict__ W2, const float* __restrict__ b2,
                           const float* __restrict__ W3, const float* __restrict__ b3,
                           const float* __restrict__ W4, const float* __restrict__ b4,
                           const float* __restrict__ W5, const float* __restrict__ b5,
                           const float* __restrict__ W6, const float* __restrict__ b6,
                           unsigned short* __restrict__ frags,
                           unsigned* __restrict__ table)
{
    int tid = blockIdx.x * 256 + threadIdx.x;

    if (tid < NFRAG * 64) {
        int frag = tid >> 6, lane = tid & 63;

        int layer, mt, ch;
        if (frag < 2)       { layer = 0; mt = frag; ch = 0; }
        else if (frag < 32) { int t = frag - 2; layer = 1 + t / 6; int r = t % 6; mt = r / 3; ch = r % 3; }
        else                { layer = 6; mt = 0; ch = frag - 32; }

        const float* Ws[7] = { W0, W1, W2, W3, W4, W5, W6 };
        const float* bs[7] = { b0, b1, b2, b3, b4, b5, b6 };
        const float* W = Ws[layer];
        const float* b = bs[layer];
        const int fout = (layer == 6) ? 3 : 40;

        int jout  = mt * 32 + (lane & 31);
        int kbase = ch * 16 + (lane >> 5) * 8;

        unsigned short h[8];
        for (int i = 0; i < 8; ++i) {
            int k = kbase + i;
            float v = 0.0f;
            if (jout < fout) {
                int jin;
                if (layer == 0) jin = (k < 3) ? k : ((k == 3) ? -2 : ((k == 4) ? -3 : -1));
                else            jin = INV[k];
                bool ex = false;
                if (layer < 6) {
                    int kp = KAP[jout];
                    int P = 4 * (kp >> 4) + ((kp & 7) >> 1);   // == Bf word index
                    ex = (P < SEXP);
                }
                float scale = (layer == 6) ? 1.0f : (ex ? EXPSC : INVH);
                if (jin >= 0)       v = W[jin * fout + jout] * scale;
                else if (jin == -2) v = b[jout] * scale;
                else if (jin == -3) v = (layer == 6 || ex) ? 0.0f : UOFF;
            }
            _Float16 hv = (_Float16)v;
            h[i] = __builtin_bit_cast(unsigned short, hv);
        }
        unsigned short* dst = frags + frag * 512 + lane * 8;
        for (int i = 0; i < 8; ++i) dst[i] = h[i];
    }
    else if (tid < NFRAG * 64 + TABN) {
        int i = tid - NFRAG * 64;
        const float H = 1.0f / 32.0f;
        float x  = -TABR + (float)i * H;
        float t0 = tanhf(x);
        float t1 = tanhf(x + H);
        float MID = 0.5f * (1.0f + tanhf(TABR));
        float base = t0, delta = t1 - t0;
        if (i == 0)        { base = -MID; delta = t1 - base; }   // left clamp midpoint
        if (i == TABN - 2) { delta = MID - t0; }                 // right clamp midpoint
        unsigned short bb = __builtin_bit_cast(unsigned short, (_Float16)base);
        unsigned short dd = __builtin_bit_cast(unsigned short, (_Float16)delta);
        table[i] = (unsigned)bb | ((unsigned)dd << 16);          // unreplicated, 900 B
    }
}

__device__ __forceinline__ unsigned int pkf16(float a, float b) {
    return __builtin_bit_cast(unsigned int, __builtin_amdgcn_cvt_pkrtz(a, b));
}
__device__ __forceinline__ f32x16 zf() {
    f32x16 v;
    #pragma unroll
    for (int i = 0; i < 16; ++i) v[i] = 0.0f;
    return v;
}
__device__ __forceinline__ float exp2_fast(float y) {
#if __has_builtin(__builtin_amdgcn_exp2f)
    return __builtin_amdgcn_exp2f(y);
#else
    float e;
    asm("v_exp_f32 %0, %1" : "=v"(e) : "v"(y));
    return e;
#endif
}
__device__ __forceinline__ f16x8 mkf(unsigned a, unsigned b, unsigned c, unsigned d) {
    u32x4 t = { a, b, c, d };
    return __builtin_bit_cast(f16x8, t);
}
// lerp-consume: f32 fract times f16 delta (entry hi) plus f16 base (entry lo),
// rounded to f16 into lo/hi halves of one B-fragment word
__device__ __forceinline__ unsigned mix2(float fa, float fb, unsigned ea, unsigned eb) {
    unsigned r;
    asm("v_fma_mixlo_f16 %0, %1, %2, %2 op_sel:[0,1,0] op_sel_hi:[0,1,1]"
        : "=v"(r) : "v"(fa), "v"(ea));
    asm("v_fma_mixhi_f16 %0, %1, %2, %2 op_sel:[0,1,0] op_sel_hi:[0,1,1]"
        : "+v"(r) : "v"(fb), "v"(eb));
    return r;
}

#define MFMA __builtin_amdgcn_mfma_f32_32x32x16_f16

// activation pack: 12 NAMED u32 fields (field-wise SROA, r11-proven)
struct BfT { unsigned w0, w1, w2, w3, w4, w5, w6, w7, w8, w9, w10, w11; };

#define BFC0(B) mkf((B).w0, (B).w1, (B).w2,  (B).w3)
#define BFC1(B) mkf((B).w4, (B).w5, (B).w6,  (B).w7)
#define BFC2(B) mkf((B).w8, (B).w9, (B).w10, (B).w11)

// issue phase: clamp, fract, index, ds_read (NO consumer here)
#define TLD(ua, ub, fa, fb, ea, eb) do {              \
    float _ca = __builtin_amdgcn_fmed3f((ua), 0.0f, UMAX); \
    float _cb = __builtin_amdgcn_fmed3f((ub), 0.0f, UMAX); \
    fa = __builtin_amdgcn_fractf(_ca);                \
    fb = __builtin_amdgcn_fractf(_cb);                \
    ea = tb[(unsigned)_ca * TABREP];                  \
    eb = tb[(unsigned)_cb * TABREP];                  \
} while (0)

// one 32-point tile of a hidden layer, phase-split (r13):
// D1 mfma -> D1 loads -> D0 mfma -> D0 loads -> exp words -> all mixes
#define HID_TILE(B) do {                              \
    f16x8 B0 = BFC0(B), B1 = BFC1(B), B2 = BFC2(B);   \
    float f8a, f8b, f9a, f9b;                         \
    unsigned e8a, e8b, e9a, e9b;                      \
    {                                                 \
        f32x16 D1 = MFMA(F3, B0, CZ, 0, 0, 0);        \
        D1 = MFMA(F4, B1, D1, 0, 0, 0);               \
        D1 = MFMA(F5, B2, D1, 0, 0, 0);               \
        TLD(D1[0], D1[1], f8a, f8b, e8a, e8b);        \
        TLD(D1[2], D1[3], f9a, f9b, e9a, e9b);        \
    }                                                 \
    {                                                 \
        f32x16 D0 = MFMA(F0, B0, CZ, 0, 0, 0);        \
        D0 = MFMA(F1, B1, D0, 0, 0, 0);               \
        D0 = MFMA(F2, B2, D0, 0, 0, 0);               \
        float f2a, f2b, f3a, f3b, f4a, f4b, f5a, f5b, f6a, f6b, f7a, f7b; \
        unsigned e2a, e2b, e3a, e3b, e4a, e4b, e5a, e5b, e6a, e6b, e7a, e7b; \
        TLD(D0[4],  D0[5],  f2a, f2b, e2a, e2b);      \
        TLD(D0[6],  D0[7],  f3a, f3b, e3a, e3b);      \
        TLD(D0[8],  D0[9],  f4a, f4b, e4a, e4b);      \
        TLD(D0[10], D0[11], f5a, f5b, e5a, e5b);      \
        TLD(D0[12], D0[13], f6a, f6b, e6a, e6b);      \
        TLD(D0[14], D0[15], f7a, f7b, e7a, e7b);      \
        (B).w0 = pkf16(te(D0[0]), te(D0[1]));         \
        (B).w1 = pkf16(te(D0[2]), te(D0[3]));         \
        (B).w2 = mix2(f2a, f2b, e2a, e2b);            \
        (B).w3 = mix2(f3a, f3b, e3a, e3b);            \
        (B).w4 = mix2(f4a, f4b, e4a, e4b);            \
        (B).w5 = mix2(f5a, f5b, e5a, e5b);            \
        (B).w6 = mix2(f6a, f6b, e6a, e6b);            \
        (B).w7 = mix2(f7a, f7b, e7a, e7b);            \
    }                                                 \
    (B).w8  = mix2(f8a, f8b, e8a, e8b);               \
    (B).w9  = mix2(f9a, f9b, e9a, e9b);               \
    (B).w10 = PK11;                                   \
    (B).w11 = 0u;                                     \
} while (0)

// layer 0 tile: same phase structure, single B chunk
#define L0_TILE(B) do {                               \
    f16x8 bb = BFC0(B);                               \
    float f8a, f8b, f9a, f9b;                         \
    unsigned e8a, e8b, e9a, e9b;                      \
    {                                                 \
        f32x16 D1 = MFMA(F1, bb, CZ, 0, 0, 0);        \
        TLD(D1[0], D1[1], f8a, f8b, e8a, e8b);        \
        TLD(D1[2], D1[3], f9a, f9b, e9a, e9b);        \
    }                                                 \
    {                                                 \
        f32x16 D0 = MFMA(F0, bb, CZ, 0, 0, 0);        \
        float f2a, f2b, f3a, f3b, f4a, f4b, f5a, f5b, f6a, f6b, f7a, f7b; \
        unsigned e2a, e2b, e3a, e3b, e4a, e4b, e5a, e5b, e6a, e6b, e7a, e7b; \
        TLD(D0[4],  D0[5],  f2a, f2b, e2a, e2b);      \
        TLD(D0[6],  D0[7],  f3a, f3b, e3a, e3b);      \
        TLD(D0[8],  D0[9],  f4a, f4b, e4a, e4b);      \
        TLD(D0[10], D0[11], f5a, f5b, e5a, e5b);      \
        TLD(D0[12], D0[13], f6a, f6b, e6a, e6b);      \
        TLD(D0[14], D0[15], f7a, f7b, e7a, e7b);      \
        (B).w0 = pkf16(te(D0[0]), te(D0[1]));         \
        (B).w1 = pkf16(te(D0[2]), te(D0[3]));         \
        (B).w2 = mix2(f2a, f2b, e2a, e2b);            \
        (B).w3 = mix2(f3a, f3b, e3a, e3b);            \
        (B).w4 = mix2(f4a, f4b, e4a, e4b);            \
        (B).w5 = mix2(f5a, f5b, e5a, e5b);            \
        (B).w6 = mix2(f6a, f6b, e6a, e6b);            \
        (B).w7 = mix2(f7a, f7b, e7a, e7b);            \
    }                                                 \
    (B).w8  = mix2(f8a, f8b, e8a, e8b);               \
    (B).w9  = mix2(f9a, f9b, e9a, e9b);               \
    (B).w10 = PK11;                                   \
    (B).w11 = 0u;                                     \
} while (0)

// one 32-point tile of the final layer (rows 0..2, lane<32)
#define FIN_TILE(B, pX, vX) do {                      \
    f32x16 D0 = MFMA(F0, BFC0(B), CZ, 0, 0, 0);       \
    D0 = MFMA(F1, BFC1(B), D0, 0, 0, 0);              \
    D0 = MFMA(F2, BFC2(B), D0, 0, 0, 0);              \
    if (lane < 32 && vX) {                            \
        out[(pX) * 3 + 0] = D0[0];                    \
        out[(pX) * 3 + 1] = D0[1];                    \
        out[(pX) * 3 + 2] = D0[2];                    \
    }                                                 \
} while (0)

__global__ __launch_bounds__(512) void mlp_mfma(const float* __restrict__ coords,
                                                const unsigned short* __restrict__ frags,
                                                const unsigned* __restrict__ gtab,
                                                float* __restrict__ out, int npts)
{
    // LDS = tanh table ONLY (28800 B)
    __shared__ __align__(16) unsigned stab[TABN * TABREP];
    {
        for (int i = threadIdx.x; i < TABN * TABREP; i += 512) stab[i] = gtab[i >> 5];
    }
    __syncthreads();

    const int lane = threadIdx.x & 63;
    const int wid  = threadIdx.x >> 6;
    const int pA   = (blockIdx.x * 8 + wid) * 64 + (lane & 31);
    const int pB   = pA + 32;
    const bool vA = (pA < npts), vB = (pB < npts);

    const unsigned int PK11 = pkf16(1.0f, 1.0f);
    const unsigned* __restrict__ tb = stab + (lane & 31);   // bank = lane&31 always
    const f32x16 CZ = zf();

    // exp path: y = 2x/ln2 from MFMA; tanh = 1 - 2/(1+2^y). Exact, no clamp.
    auto te = [&](float y) -> float {
        float e = exp2_fast(y);
        float r = __builtin_amdgcn_rcpf(e + 1.0f);
        return __builtin_fmaf(-2.0f, r, 1.0f);
    };

    BfT A, B;
    {
        float a0 = 0.f, a1 = 0.f, a2 = 0.f, b0 = 0.f, b1 = 0.f, b2 = 0.f;
        if (vA) { a0 = coords[pA * 3]; a1 = coords[pA * 3 + 1]; a2 = coords[pA * 3 + 2]; }
        if (vB) { b0 = coords[pB * 3]; b1 = coords[pB * 3 + 1]; b2 = coords[pB * 3 + 2]; }
        A.w0 = pkf16(a0, a1); A.w1 = pkf16(a2, 1.0f);
        B.w0 = pkf16(b0, b1); B.w1 = pkf16(b2, 1.0f);
        A.w2 = B.w2 = pkf16(1.0f, 0.0f);
        A.w3 = B.w3 = 0u;
    }

    // weight fragments from GLOBAL (d_ws): per-lane coalesced 16B loads,
    // same addresses for every wave -> L1/L2-resident (35 KB total)
    auto AF = [&](int f) -> f16x8 {
        return ((const f16x8*)frags)[f * 64 + lane];
    };

    f16x8 F0, F1, F2, F3, F4, F5;

    // ---- layer 0
    F0 = AF(0); F1 = AF(1);
    L0_TILE(A); L0_TILE(B);

    // ---- hidden layers 1..5
    #pragma unroll
    for (int l = 1; l <= 5; ++l) {
        const int fb = 2 + (l - 1) * 6;
        F0 = AF(fb + 0); F1 = AF(fb + 1); F2 = AF(fb + 2);
        F3 = AF(fb + 3); F4 = AF(fb + 4); F5 = AF(fb + 5);
        HID_TILE(A); HID_TILE(B);
    }

    // ---- layer 6: [40] -> [3], true scale, no tanh
    F0 = AF(32); F1 = AF(33); F2 = AF(34);
    FIN_TILE(A, pA, vA);
    FIN_TILE(B, pB, vB);
}

extern "C" void kernel_launch(void* const* d_in, const int* in_sizes, int n_in,
                              void* d_out, int out_size, void* d_ws, size_t ws_size,
                              hipStream_t stream)
{
    const float* coords = (const float*)d_in[0];
    const float* W0 = (const float*)d_in[1];  const float* b0 = (const float*)d_in[2];
    const float* W1 = (const float*)d_in[3];  const float* b1 = (const float*)d_in[4];
    const float* W2 = (const float*)d_in[5];  const float* b2 = (const float*)d_in[6];
    const float* W3 = (const float*)d_in[7];  const float* b3 = (const float*)d_in[8];
    const float* W4 = (const float*)d_in[9];  const float* b4 = (const float*)d_in[10];
    const float* W5 = (const float*)d_in[11]; const float* b5 = (const float*)d_in[12];
    const float* W6 = (const float*)d_in[13]; const float* b6 = (const float*)d_in[14];
    float* out = (float*)d_out;

    unsigned short* frags = (unsigned short*)d_ws;                      // 35840 B
    unsigned* table = (unsigned*)((char*)d_ws + NFRAG * 1024);          // 900 B

    const int npts = in_sizes[0] / 3;

    const int prep_threads = NFRAG * 64 + TABN;
    prep_frags<<<(prep_threads + 255) / 256, 256, 0, stream>>>(
        W0, b0, W1, b1, W2, b2, W3, b3, W4, b4, W5, b5, W6, b6, frags, table);

    const int blocks = (npts + 511) / 512;   // 512 points per block (8 waves x 64)
    mlp_mfma<<<blocks, 512, 0, stream>>>(coords, frags, table, out, npts);
}